// Round 1
// baseline (252.543 us; speedup 1.0000x reference)
//
#include <hip/hip_runtime.h>
#include <hip/hip_bf16.h>
#include <math.h>

// SpectralGate1D: out[:, -64:, :] = circconv64(x[:, -64:, :], h_d) * mix_w[d]
// where h_d = irfft(sigmoid(mask[d,:])) (real gate -> zero-phase circular filter).
// Everything else in out is zero.

#define BB 8
#define TT 4096
#define DD 1024
#define KK 64
#define NF 33   // K/2+1

__global__ __launch_bounds__(256) void SpectralGate1D_conv_kernel(
    const float* __restrict__ x,
    const float* __restrict__ mask,
    const float* __restrict__ mix_w,
    float* __restrict__ out)
{
    __shared__ float g_lds[64][NF];   // sigmoid(mask) per local channel
    __shared__ float ct[64];          // cos(2*pi*m/64) table
    __shared__ float x_lds[64][64];   // [n][d_local] window samples
    __shared__ float h_lds[64][64];   // [m][d_local] filter taps

    const int b  = blockIdx.x;        // 0..7
    const int d0 = blockIdx.y * 64;   // channel tile base
    const int tid = threadIdx.x;      // 0..255
    const int dl = tid & 63;          // lane -> channel (coalesced)
    const int tg = tid >> 6;          // wave id -> time group

    // cos table: ct[m] = cos(2*pi*m/64)
    if (tid < 64) ct[tid] = cosf((float)tid * (float)(M_PI / 32.0));

    // gate = sigmoid(mask): 64*33 entries, cooperative load
    for (int i = tid; i < 64 * NF; i += 256) {
        const int d = i / NF;
        const int k = i - d * NF;
        const float m = mask[(size_t)(d0 + d) * NF + k];
        g_lds[d][k] = 1.0f / (1.0f + expf(-m));
    }

    // x window: x[b, T-64+n, d0+dl]  (coalesced across dl)
    const float* xb = x + ((size_t)b * TT + (TT - KK)) * (size_t)DD + d0;
    #pragma unroll
    for (int i = 0; i < 16; ++i) {
        const int n = tg * 16 + i;
        x_lds[n][dl] = xb[(size_t)n * DD + dl];
    }
    __syncthreads();

    // h[m][d] = (1/64)*(g0 + 2*sum_{k=1..31} gk*cos(2*pi*k*m/64) + g32*(-1)^m) * mix_w[d]
    const float scale = mix_w[d0 + dl] * (1.0f / 64.0f);  // GATE_STRENGTH = 1.0
    #pragma unroll
    for (int i = 0; i < 16; ++i) {
        const int m = tg * 16 + i;
        float s = g_lds[dl][0];
        #pragma unroll
        for (int k = 1; k < 32; ++k) {
            s += 2.0f * g_lds[dl][k] * ct[(k * m) & 63];   // ct read is wave-uniform
        }
        s += g_lds[dl][32] * ct[(32 * m) & 63];            // = (-1)^m
        h_lds[m][dl] = s * scale;
    }
    __syncthreads();

    // circular convolution: y[t] = sum_n x[n] * h[(t-n) mod 64]
    float* ob = out + ((size_t)b * TT + (TT - KK)) * (size_t)DD + d0;
    #pragma unroll
    for (int i = 0; i < 16; ++i) {
        const int t = tg * 16 + i;
        float acc = 0.0f;
        #pragma unroll
        for (int n = 0; n < 64; ++n) {
            acc += x_lds[n][dl] * h_lds[(t - n) & 63][dl];
        }
        ob[(size_t)t * DD + dl] = acc;                      // coalesced store
    }
}

extern "C" void kernel_launch(void* const* d_in, const int* in_sizes, int n_in,
                              void* d_out, int out_size, void* d_ws, size_t ws_size,
                              hipStream_t stream) {
    const float* x     = (const float*)d_in[0];   // (8, 4096, 1024) fp32
    const float* mask  = (const float*)d_in[1];   // (1024, 33) fp32
    const float* mix_w = (const float*)d_in[2];   // (1024,) fp32
    float* out = (float*)d_out;                   // (8, 4096, 1024) fp32

    // Zero the whole output (poisoned 0xAA before every launch); the conv
    // kernel then overwrites the last 64 time rows.
    hipMemsetAsync(out, 0, (size_t)out_size * sizeof(float), stream);

    dim3 grid(BB, DD / 64);   // 8 x 16 = 128 blocks
    dim3 block(256);
    SpectralGate1D_conv_kernel<<<grid, block, 0, stream>>>(x, mask, mix_w, out);
}